// Round 1
// baseline (361.384 us; speedup 1.0000x reference)
//
#include <hip/hip_runtime.h>
#include <hip/hip_bf16.h>

#define NEG_SLOPE 0.2f

__device__ __forceinline__ float leaky(float v) {
    return v > 0.f ? v : NEG_SLOPE * v;
}

__device__ __forceinline__ float wave_sum(float v) {
    for (int off = 32; off; off >>= 1) v += __shfl_xor(v, off);
    return v;
}

__device__ __forceinline__ float wave_max(float v) {
    for (int off = 32; off; off >>= 1) v = fmaxf(v, __shfl_xor(v, off));
    return v;
}

// ---------------------------------------------------------------- zero init
__global__ __launch_bounds__(256) void k_zero(int* __restrict__ deg,
                                              int* __restrict__ cursor, int n) {
    int i = blockIdx.x * 256 + threadIdx.x;
    if (i < n) { deg[i] = 0; cursor[i] = 0; }
}

// ------------------------------------------------- h = x@W, a_src, a_dst
// one wave computes 4 rows; lane = output column (DIM_OUT = 64 = wave size)
__global__ __launch_bounds__(256) void k_gemm(
    const float* __restrict__ x, const float* __restrict__ Wg,
    const float* __restrict__ att_s, const float* __restrict__ att_d,
    float* __restrict__ h, float* __restrict__ a_src, float* __restrict__ a_dst,
    int n) {
    __shared__ float Wl[128 * 64];  // 32 KB
    {
        const float4* s4 = (const float4*)Wg;
        float4* d4 = (float4*)Wl;
        for (int i = threadIdx.x; i < 128 * 64 / 4; i += 256) d4[i] = s4[i];
    }
    __syncthreads();
    const int lane = threadIdx.x & 63;
    const float as_l = att_s[lane];
    const float ad_l = att_d[lane];
    int gw = (blockIdx.x << 2) + (threadIdx.x >> 6);
    int r0 = __builtin_amdgcn_readfirstlane(gw << 2);
    if (r0 >= n) return;
    if (r0 + 4 <= n) {
        const float* __restrict__ xr = x + (size_t)r0 * 128;
        float acc0 = 0.f, acc1 = 0.f, acc2 = 0.f, acc3 = 0.f;
        for (int k = 0; k < 128; k += 4) {
            float w0 = Wl[(k + 0) * 64 + lane];
            float w1 = Wl[(k + 1) * 64 + lane];
            float w2 = Wl[(k + 2) * 64 + lane];
            float w3 = Wl[(k + 3) * 64 + lane];
            float4 x0 = *(const float4*)(xr + k);
            float4 x1 = *(const float4*)(xr + 128 + k);
            float4 x2 = *(const float4*)(xr + 256 + k);
            float4 x3 = *(const float4*)(xr + 384 + k);
            acc0 += x0.x * w0 + x0.y * w1 + x0.z * w2 + x0.w * w3;
            acc1 += x1.x * w0 + x1.y * w1 + x1.z * w2 + x1.w * w3;
            acc2 += x2.x * w0 + x2.y * w1 + x2.z * w2 + x2.w * w3;
            acc3 += x3.x * w0 + x3.y * w1 + x3.z * w2 + x3.w * w3;
        }
        float* hp = h + (size_t)r0 * 64 + lane;
        hp[0] = acc0; hp[64] = acc1; hp[128] = acc2; hp[192] = acc3;
        float s;
        s = wave_sum(acc0 * as_l); if (!lane) a_src[r0 + 0] = s;
        s = wave_sum(acc0 * ad_l); if (!lane) a_dst[r0 + 0] = s;
        s = wave_sum(acc1 * as_l); if (!lane) a_src[r0 + 1] = s;
        s = wave_sum(acc1 * ad_l); if (!lane) a_dst[r0 + 1] = s;
        s = wave_sum(acc2 * as_l); if (!lane) a_src[r0 + 2] = s;
        s = wave_sum(acc2 * ad_l); if (!lane) a_dst[r0 + 2] = s;
        s = wave_sum(acc3 * as_l); if (!lane) a_src[r0 + 3] = s;
        s = wave_sum(acc3 * ad_l); if (!lane) a_dst[r0 + 3] = s;
    } else {
        for (int rr = 0; rr < 4 && r0 + rr < n; ++rr) {
            const float* xp = x + (size_t)(r0 + rr) * 128;
            float acc = 0.f;
            for (int k = 0; k < 128; ++k) acc += xp[k] * Wl[k * 64 + lane];
            h[(size_t)(r0 + rr) * 64 + lane] = acc;
            float s = wave_sum(acc * as_l); if (!lane) a_src[r0 + rr] = s;
            float t = wave_sum(acc * ad_l); if (!lane) a_dst[r0 + rr] = t;
        }
    }
}

// ---------------------------------------------------------------- histogram
__global__ __launch_bounds__(256) void k_hist(const int* __restrict__ dstv,
                                              int* __restrict__ deg, int e) {
    int i = blockIdx.x * 256 + threadIdx.x;
    if (i < e) atomicAdd(&deg[dstv[i]], 1);
}

// ------------------------------------------------- exclusive scan (3-phase)
__global__ __launch_bounds__(256) void k_scan1(const int* __restrict__ in,
                                               int* __restrict__ outp,
                                               int* __restrict__ partials, int n) {
    __shared__ int sd[256];
    const int tid = threadIdx.x;
    const int base = blockIdx.x * 2048 + tid * 8;
    int v[8]; int tot = 0;
#pragma unroll
    for (int i = 0; i < 8; ++i) {
        int idx = base + i;
        v[i] = (idx < n) ? in[idx] : 0;
        tot += v[i];
    }
    sd[tid] = tot;
    __syncthreads();
    for (int off = 1; off < 256; off <<= 1) {
        int t = (tid >= off) ? sd[tid - off] : 0;
        __syncthreads();
        sd[tid] += t;
        __syncthreads();
    }
    int run = sd[tid] - tot;  // exclusive across threads within block
#pragma unroll
    for (int i = 0; i < 8; ++i) {
        int idx = base + i;
        if (idx < n) outp[idx] = run;
        run += v[i];
    }
    if (tid == 255) partials[blockIdx.x] = sd[255];
}

// single-wave exclusive scan of block partials (nb <= 64 required)
__global__ void k_scan2(int* __restrict__ partials, int nb) {
    int lane = threadIdx.x;
    int v = (lane < nb) ? partials[lane] : 0;
    int orig = v;
    for (int off = 1; off < 64; off <<= 1) {
        int t = __shfl_up(v, off);
        if (lane >= off) v += t;
    }
    if (lane < nb) partials[lane] = v - orig;
}

__global__ __launch_bounds__(256) void k_scan3(int* __restrict__ outp,
                                               const int* __restrict__ partials,
                                               int n, int etotal) {
    int add = partials[blockIdx.x];
    const int base = blockIdx.x * 2048 + threadIdx.x * 8;
#pragma unroll
    for (int i = 0; i < 8; ++i) {
        int idx = base + i;
        if (idx < n) outp[idx] += add;
    }
    if (blockIdx.x == 0 && threadIdx.x == 0) outp[n] = etotal;
}

// ---------------------------------------------------------------- scatter
__global__ __launch_bounds__(256) void k_scatter(
    const int* __restrict__ srcv, const int* __restrict__ dstv,
    const int* __restrict__ rowptr, int* __restrict__ cursor,
    int* __restrict__ srcs, int e) {
    int i = blockIdx.x * 256 + threadIdx.x;
    if (i < e) {
        int d = dstv[i];
        int p = rowptr[d] + atomicAdd(&cursor[d], 1);
        srcs[p] = srcv[i];
    }
}

// ------------------------------------- per-destination softmax + aggregate
// one wave per node; lane = output feature dim
__global__ __launch_bounds__(256) void k_aggr(
    const float* __restrict__ h, const float* __restrict__ a_src,
    const float* __restrict__ a_dst, const int* __restrict__ rowptr,
    const int* __restrict__ srcs, float* __restrict__ out, int n) {
    const int lane = threadIdx.x & 63;
    int d = (blockIdx.x << 2) + (threadIdx.x >> 6);
    if (d >= n) return;
    d = __builtin_amdgcn_readfirstlane(d);
    const int base = rowptr[d];
    const int deg = rowptr[d + 1] - base;
    const float adst = a_dst[d];
    const float e_self = leaky(a_src[d] + adst);

    // phase 1: segment max (incl. self loop)
    float m = e_self;
    for (int c0 = 0; c0 < deg; c0 += 64) {
        int j = c0 + lane;
        if (j < deg) {
            int s = srcs[base + j];
            m = fmaxf(m, leaky(a_src[s] + adst));
        }
    }
    m = wave_max(m);

    // phase 2: denom
    float local = 0.f;
    for (int c0 = 0; c0 < deg; c0 += 64) {
        int j = c0 + lane;
        if (j < deg) {
            int s = srcs[base + j];
            local += __expf(leaky(a_src[s] + adst) - m);
        }
    }
    const float wself = __expf(e_self - m);
    const float denom = wave_sum(local) + wself;
    const float inv = 1.0f / (denom + 1e-16f);

    // phase 3: weighted aggregate (lane = feature)
    float acc = wself * inv * h[(size_t)d * 64 + lane];
    for (int c0 = 0; c0 < deg; c0 += 64) {
        int j = c0 + lane;
        int cnt = min(64, deg - c0);
        int sj = 0; float wj = 0.f;
        if (j < deg) {
            sj = srcs[base + j];
            wj = __expf(leaky(a_src[sj] + adst) - m) * inv;
        }
        for (int t = 0; t < cnt; ++t) {
            int st = __builtin_amdgcn_readlane(sj, t);
            float wt = __int_as_float(
                __builtin_amdgcn_readlane(__float_as_int(wj), t));
            acc += wt * h[(size_t)st * 64 + lane];
        }
    }
    out[(size_t)d * 64 + lane] = acc;
}

extern "C" void kernel_launch(void* const* d_in, const int* in_sizes, int n_in,
                              void* d_out, int out_size, void* d_ws, size_t ws_size,
                              hipStream_t stream) {
    const float* x = (const float*)d_in[0];
    const float* W = (const float*)d_in[1];
    const float* att_s = (const float*)d_in[2];
    const float* att_d = (const float*)d_in[3];
    const int* ei = (const int*)d_in[4];
    const int n = in_sizes[0] / 128;
    const int e = in_sizes[4] / 2;
    const int* srcv = ei;
    const int* dstv = ei + e;
    float* out = (float*)d_out;

    char* ws = (char*)d_ws;
    size_t off = 0;
    auto carve = [&](size_t bytes) -> void* {
        void* p = ws + off;
        off = (off + bytes + 63) & ~(size_t)63;
        return p;
    };
    float* h       = (float*)carve((size_t)n * 64 * 4);
    float* a_src   = (float*)carve((size_t)n * 4);
    float* a_dst   = (float*)carve((size_t)n * 4);
    int* rowptr    = (int*)carve((size_t)(n + 1) * 4);
    int* deg       = (int*)carve((size_t)n * 4);
    int* cursor    = (int*)carve((size_t)n * 4);
    int* partials  = (int*)carve(256 * 4);
    int* srcs      = (int*)carve((size_t)e * 4);
    (void)ws_size; (void)n_in; (void)out_size;

    const int nb = (n + 2047) / 2048;  // must be <= 64 (n <= 131072)

    k_zero<<<(n + 255) / 256, 256, 0, stream>>>(deg, cursor, n);
    k_gemm<<<(n + 15) / 16, 256, 0, stream>>>(x, W, att_s, att_d, h, a_src, a_dst, n);
    k_hist<<<(e + 255) / 256, 256, 0, stream>>>(dstv, deg, e);
    k_scan1<<<nb, 256, 0, stream>>>(deg, rowptr, partials, n);
    k_scan2<<<1, 64, 0, stream>>>(partials, nb);
    k_scan3<<<nb, 256, 0, stream>>>(rowptr, partials, n, e);
    k_scatter<<<(e + 255) / 256, 256, 0, stream>>>(srcv, dstv, rowptr, cursor, srcs, e);
    k_aggr<<<(n + 3) / 4, 256, 0, stream>>>(h, a_src, a_dst, rowptr, srcs, out, n);
}

// Round 2
// 305.039 us; speedup vs baseline: 1.1847x; 1.1847x over previous
//
#include <hip/hip_runtime.h>
#include <hip/hip_bf16.h>

#define NEG_SLOPE 0.2f

__device__ __forceinline__ float leaky(float v) {
    return v > 0.f ? v : NEG_SLOPE * v;
}

__device__ __forceinline__ float wave_sum(float v) {
    for (int off = 32; off; off >>= 1) v += __shfl_xor(v, off);
    return v;
}

__device__ __forceinline__ float wave_max(float v) {
    for (int off = 32; off; off >>= 1) v = fmaxf(v, __shfl_xor(v, off));
    return v;
}

// ------------------------------------------------- h = x@W, a_src, a_dst
// one wave computes 4 rows; lane = output column (DIM_OUT = 64 = wave size)
__global__ __launch_bounds__(256) void k_gemm(
    const float* __restrict__ x, const float* __restrict__ Wg,
    const float* __restrict__ att_s, const float* __restrict__ att_d,
    float* __restrict__ h, float* __restrict__ a_src, float* __restrict__ a_dst,
    int n) {
    __shared__ float Wl[128 * 64];  // 32 KB
    {
        const float4* s4 = (const float4*)Wg;
        float4* d4 = (float4*)Wl;
        for (int i = threadIdx.x; i < 128 * 64 / 4; i += 256) d4[i] = s4[i];
    }
    __syncthreads();
    const int lane = threadIdx.x & 63;
    const float as_l = att_s[lane];
    const float ad_l = att_d[lane];
    int gw = (blockIdx.x << 2) + (threadIdx.x >> 6);
    int r0 = __builtin_amdgcn_readfirstlane(gw << 2);
    if (r0 >= n) return;
    if (r0 + 4 <= n) {
        const float* __restrict__ xr = x + (size_t)r0 * 128;
        float acc0 = 0.f, acc1 = 0.f, acc2 = 0.f, acc3 = 0.f;
        for (int k = 0; k < 128; k += 4) {
            float w0 = Wl[(k + 0) * 64 + lane];
            float w1 = Wl[(k + 1) * 64 + lane];
            float w2 = Wl[(k + 2) * 64 + lane];
            float w3 = Wl[(k + 3) * 64 + lane];
            float4 x0 = *(const float4*)(xr + k);
            float4 x1 = *(const float4*)(xr + 128 + k);
            float4 x2 = *(const float4*)(xr + 256 + k);
            float4 x3 = *(const float4*)(xr + 384 + k);
            acc0 += x0.x * w0 + x0.y * w1 + x0.z * w2 + x0.w * w3;
            acc1 += x1.x * w0 + x1.y * w1 + x1.z * w2 + x1.w * w3;
            acc2 += x2.x * w0 + x2.y * w1 + x2.z * w2 + x2.w * w3;
            acc3 += x3.x * w0 + x3.y * w1 + x3.z * w2 + x3.w * w3;
        }
        float* hp = h + (size_t)r0 * 64 + lane;
        hp[0] = acc0; hp[64] = acc1; hp[128] = acc2; hp[192] = acc3;
        float s;
        s = wave_sum(acc0 * as_l); if (!lane) a_src[r0 + 0] = s;
        s = wave_sum(acc0 * ad_l); if (!lane) a_dst[r0 + 0] = s;
        s = wave_sum(acc1 * as_l); if (!lane) a_src[r0 + 1] = s;
        s = wave_sum(acc1 * ad_l); if (!lane) a_dst[r0 + 1] = s;
        s = wave_sum(acc2 * as_l); if (!lane) a_src[r0 + 2] = s;
        s = wave_sum(acc2 * ad_l); if (!lane) a_dst[r0 + 2] = s;
        s = wave_sum(acc3 * as_l); if (!lane) a_src[r0 + 3] = s;
        s = wave_sum(acc3 * ad_l); if (!lane) a_dst[r0 + 3] = s;
    } else {
        for (int rr = 0; rr < 4 && r0 + rr < n; ++rr) {
            const float* xp = x + (size_t)(r0 + rr) * 128;
            float acc = 0.f;
            for (int k = 0; k < 128; ++k) acc += xp[k] * Wl[k * 64 + lane];
            h[(size_t)(r0 + rr) * 64 + lane] = acc;
            float s = wave_sum(acc * as_l); if (!lane) a_src[r0 + rr] = s;
            float t = wave_sum(acc * ad_l); if (!lane) a_dst[r0 + rr] = t;
        }
    }
}

// ---------------------------------------------------------------- histogram
// 4 edges per thread (vectorized read)
__global__ __launch_bounds__(256) void k_hist(const int* __restrict__ dstv,
                                              int* __restrict__ deg, int e) {
    int i4 = (blockIdx.x * 256 + threadIdx.x) * 4;
    if (i4 + 4 <= e) {
        int4 d = *(const int4*)(dstv + i4);
        atomicAdd(&deg[d.x], 1);
        atomicAdd(&deg[d.y], 1);
        atomicAdd(&deg[d.z], 1);
        atomicAdd(&deg[d.w], 1);
    } else {
        for (int i = i4; i < e; ++i) atomicAdd(&deg[dstv[i]], 1);
    }
}

// ------------------------------------------------- exclusive scan (3-phase)
__global__ __launch_bounds__(256) void k_scan1(const int* __restrict__ in,
                                               int* __restrict__ outp,
                                               int* __restrict__ partials, int n) {
    __shared__ int sd[256];
    const int tid = threadIdx.x;
    const int base = blockIdx.x * 2048 + tid * 8;
    int v[8]; int tot = 0;
#pragma unroll
    for (int i = 0; i < 8; ++i) {
        int idx = base + i;
        v[i] = (idx < n) ? in[idx] : 0;
        tot += v[i];
    }
    sd[tid] = tot;
    __syncthreads();
    for (int off = 1; off < 256; off <<= 1) {
        int t = (tid >= off) ? sd[tid - off] : 0;
        __syncthreads();
        sd[tid] += t;
        __syncthreads();
    }
    int run = sd[tid] - tot;
#pragma unroll
    for (int i = 0; i < 8; ++i) {
        int idx = base + i;
        if (idx < n) outp[idx] = run;
        run += v[i];
    }
    if (tid == 255) partials[blockIdx.x] = sd[255];
}

__global__ void k_scan2(int* __restrict__ partials, int nb) {
    int lane = threadIdx.x;
    int v = (lane < nb) ? partials[lane] : 0;
    int orig = v;
    for (int off = 1; off < 64; off <<= 1) {
        int t = __shfl_up(v, off);
        if (lane >= off) v += t;
    }
    if (lane < nb) partials[lane] = v - orig;
}

__global__ __launch_bounds__(256) void k_scan3(int* __restrict__ outp,
                                               const int* __restrict__ partials,
                                               int n, int etotal) {
    int add = partials[blockIdx.x];
    const int base = blockIdx.x * 2048 + threadIdx.x * 8;
#pragma unroll
    for (int i = 0; i < 8; ++i) {
        int idx = base + i;
        if (idx < n) outp[idx] += add;
    }
    if (blockIdx.x == 0 && threadIdx.x == 0) outp[n] = etotal;
}

// ---------------------------------------------------------------- scatter
// also pre-gathers a_src[src] into vals[] so softmax passes stream contiguously
__global__ __launch_bounds__(256) void k_scatter(
    const int* __restrict__ srcv, const int* __restrict__ dstv,
    const float* __restrict__ a_src,
    const int* __restrict__ rowptr, int* __restrict__ cursor,
    int* __restrict__ srcs, float* __restrict__ vals, int e) {
    int i = blockIdx.x * 256 + threadIdx.x;
    if (i < e) {
        int d = dstv[i];
        int s = srcv[i];
        int p = rowptr[d] + atomicAdd(&cursor[d], 1);
        srcs[p] = s;
        vals[p] = a_src[s];
    }
}

// ------------------------------------- per-destination softmax + aggregate
// one wave per node; phase 3: 4 rows/iter, lane = (row r, feature-quad f0)
__global__ __launch_bounds__(256) void k_aggr(
    const float* __restrict__ h, const float* __restrict__ a_src,
    const float* __restrict__ a_dst, const int* __restrict__ rowptr,
    const int* __restrict__ srcs, const float* __restrict__ vals,
    float* __restrict__ out, int n) {
    const int lane = threadIdx.x & 63;
    int d = (blockIdx.x << 2) + (threadIdx.x >> 6);
    if (d >= n) return;
    d = __builtin_amdgcn_readfirstlane(d);
    const int base = rowptr[d];
    const int deg = rowptr[d + 1] - base;
    const float adst = a_dst[d];
    const float e_self = leaky(a_src[d] + adst);

    // single online max+sum pass over contiguous vals
    float lm = -1e30f, ls = 0.f;
    for (int j = lane; j < deg; j += 64) {
        float ev = leaky(vals[base + j] + adst);
        if (ev > lm) {
            ls = ls * __expf(lm - ev) + 1.f;
            lm = ev;
        } else {
            ls += __expf(ev - lm);
        }
    }
    const float m = fmaxf(wave_max(lm), e_self);
    ls *= __expf(lm - m);
    const float denom = wave_sum(ls) + __expf(e_self - m);
    const float inv = 1.0f / (denom + 1e-16f);

    // phase 3: 4 rows per iteration, float4 per lane
    const int r = lane >> 4;          // row group 0..3
    const int f0 = (lane & 15) << 2;  // feature quad
    float4 acc = {0.f, 0.f, 0.f, 0.f};
    if (r == 0) {  // self loop handled by row-group 0
        float w = __expf(e_self - m) * inv;
        const float4 hv = *(const float4*)(h + (size_t)d * 64 + f0);
        acc.x = w * hv.x; acc.y = w * hv.y; acc.z = w * hv.z; acc.w = w * hv.w;
    }
    for (int c0 = 0; c0 < deg; c0 += 4) {
        int j = c0 + r;
        if (j < deg) {
            int s = srcs[base + j];
            float w = __expf(leaky(vals[base + j] + adst) - m) * inv;
            const float4 hv = *(const float4*)(h + (size_t)s * 64 + f0);
            acc.x += w * hv.x; acc.y += w * hv.y;
            acc.z += w * hv.z; acc.w += w * hv.w;
        }
    }
    // combine the 4 row groups: lanes l, l^16, l^32, l^48
    acc.x += __shfl_xor(acc.x, 16); acc.y += __shfl_xor(acc.y, 16);
    acc.z += __shfl_xor(acc.z, 16); acc.w += __shfl_xor(acc.w, 16);
    acc.x += __shfl_xor(acc.x, 32); acc.y += __shfl_xor(acc.y, 32);
    acc.z += __shfl_xor(acc.z, 32); acc.w += __shfl_xor(acc.w, 32);
    if (lane < 16) *(float4*)(out + (size_t)d * 64 + f0) = acc;
}

extern "C" void kernel_launch(void* const* d_in, const int* in_sizes, int n_in,
                              void* d_out, int out_size, void* d_ws, size_t ws_size,
                              hipStream_t stream) {
    const float* x = (const float*)d_in[0];
    const float* W = (const float*)d_in[1];
    const float* att_s = (const float*)d_in[2];
    const float* att_d = (const float*)d_in[3];
    const int* ei = (const int*)d_in[4];
    const int n = in_sizes[0] / 128;
    const int e = in_sizes[4] / 2;
    const int* srcv = ei;
    const int* dstv = ei + e;
    float* out = (float*)d_out;

    char* ws = (char*)d_ws;
    size_t off = 0;
    auto carve = [&](size_t bytes) -> void* {
        void* p = ws + off;
        off = (off + bytes + 63) & ~(size_t)63;
        return p;
    };
    float* h       = (float*)carve((size_t)n * 64 * 4);
    float* a_src   = (float*)carve((size_t)n * 4);
    float* a_dst   = (float*)carve((size_t)n * 4);
    int* rowptr    = (int*)carve((size_t)(n + 1) * 4);
    int* deg       = (int*)carve((size_t)n * 4);   // deg+cursor contiguous
    int* cursor    = (int*)carve((size_t)n * 4);
    int* partials  = (int*)carve(256 * 4);
    int* srcs      = (int*)carve((size_t)e * 4);
    float* vals    = (float*)carve((size_t)e * 4);
    (void)ws_size; (void)n_in; (void)out_size;

    const int nb = (n + 2047) / 2048;  // <= 64 for n <= 131072

    // zero deg + cursor (contiguous carves, both n ints, 64B-aligned gap safe:
    // zero the full span from deg to end of cursor)
    size_t zspan = (size_t)((char*)(cursor + n) - (char*)deg);
    hipMemsetAsync(deg, 0, zspan, stream);

    k_gemm<<<(n + 15) / 16, 256, 0, stream>>>(x, W, att_s, att_d, h, a_src, a_dst, n);
    k_hist<<<(e / 4 + 255) / 256, 256, 0, stream>>>(dstv, deg, e);
    k_scan1<<<nb, 256, 0, stream>>>(deg, rowptr, partials, n);
    k_scan2<<<1, 64, 0, stream>>>(partials, nb);
    k_scan3<<<nb, 256, 0, stream>>>(rowptr, partials, n, e);
    k_scatter<<<(e + 255) / 256, 256, 0, stream>>>(srcv, dstv, a_src, rowptr, cursor, srcs, vals, e);
    k_aggr<<<(n + 3) / 4, 256, 0, stream>>>(h, a_src, a_dst, rowptr, srcs, vals, out, n);
}